// Round 1
// 801.459 us; speedup vs baseline: 1.2830x; 1.2830x over previous
//
#include <hip/hip_runtime.h>
#include <stdint.h>

#define B_TOK 32768
#define IN    128
#define HID   128
#define NE    32
#define NC    128

typedef __attribute__((ext_vector_type(8))) __bf16 bf16x8;
typedef __attribute__((ext_vector_type(4))) float  f32x4;

static __device__ __forceinline__ unsigned short f2bf(float f) {
    union { float f; uint32_t u; } v; v.f = f;
    uint32_t u = v.u;
    return (unsigned short)((u + 0x7FFFu + ((u >> 16) & 1u)) >> 16);
}

// ---- prep: x fp32 -> bf16 --------------------------------------------------
__global__ void k_convert_x(const float* __restrict__ x, unsigned short* __restrict__ xb) {
    int i = (blockIdx.x * 256 + threadIdx.x) * 4;
    float4 v = *(const float4*)(x + i);
    ushort4 o;
    o.x = f2bf(v.x); o.y = f2bf(v.y); o.z = f2bf(v.z); o.w = f2bf(v.w);
    *(ushort4*)(xb + i) = o;
}

// ---- prep: W1T[e][h][i] = bf16(W1[e][i][h]) --------------------------------
__global__ void k_prep_w1t(const float* __restrict__ W1, unsigned short* __restrict__ W1T) {
    int idx = blockIdx.x * 256 + threadIdx.x;   // e*16384 + h*128 + i
    int i = idx & 127;
    int h = (idx >> 7) & 127;
    int e = idx >> 14;
    W1T[idx] = f2bf(W1[(e * 128 + i) * 128 + h]);
}

// ---- prep: W2cT[e][c][h] = bf16(sum_t W2[e][h][t]*Wc[t][c]); bc2 fold ------
__global__ void k_prep_w2c(const float* __restrict__ W2, const float* __restrict__ Wc,
                           const float* __restrict__ b2, const float* __restrict__ bc,
                           unsigned short* __restrict__ W2cT, float* __restrict__ bc2) {
    __shared__ float row[128];
    int e = blockIdx.x >> 7, h = blockIdx.x & 127;   // grid 32*128
    int c = threadIdx.x;                              // 128 threads
    row[c] = W2[(e * 128 + h) * 128 + c];
    __syncthreads();
    float acc = 0.f;
    #pragma unroll 8
    for (int t = 0; t < 128; ++t) acc += row[t] * Wc[t * 128 + c];   // row[t] broadcast, Wc coalesced
    W2cT[(e * 128 + c) * 128 + h] = f2bf(acc);
    if (h == 0) {
        float a2 = bc[c];
        for (int t = 0; t < 128; ++t) a2 += b2[e * 128 + t] * Wc[t * 128 + c];
        bc2[e * 128 + c] = a2;
    }
}

// ---- router: scores = softmax(relu(x @ Wg + bg), axis=1) -------------------
__global__ __launch_bounds__(256) void k_router(const float* __restrict__ x,
        const float* __restrict__ Wg, const float* __restrict__ bg,
        float* __restrict__ scores) {
    __shared__ float Wgs[128 * 32];
    __shared__ float xs[8][128];
    int tid = threadIdx.x;
    for (int j = tid; j < 4096; j += 256) Wgs[j] = Wg[j];
    int rb = blockIdx.x * 8;
    for (int j = tid; j < 8 * 128; j += 256)
        xs[j >> 7][j & 127] = x[(rb + (j >> 7)) * 128 + (j & 127)];
    __syncthreads();
    int r = tid >> 5;        // 0..7 row in tile
    int e = tid & 31;        // expert
    float acc = bg[e];
    #pragma unroll 8
    for (int i = 0; i < 128; ++i) acc += xs[r][i] * Wgs[i * 32 + e];
    acc = fmaxf(acc, 0.f);
    float m = acc;
    for (int off = 16; off > 0; off >>= 1) m = fmaxf(m, __shfl_xor(m, off, 32));
    float p = __expf(acc - m);
    float s = p;
    for (int off = 16; off > 0; off >>= 1) s += __shfl_xor(s, off, 32);
    scores[(size_t)(rb + r) * 32 + e] = p / s;
}

// ---- main fused: out[:,e,:] = relu(X@W1[e]+b1[e]) @ W2c[e] + bc2[e] --------
// v2: swapped MFMA operands (A = weight frags, B = X/H frags).
//  - wave owns 64 rows (4 A-tiles in regs): each weight fragment feeds 16
//    independent MFMAs (was 4) -> 4x less L2 weight traffic + deep ILP.
//  - D layout (col=lane&15, row=quad*4+reg) now puts 4 consecutive output
//    cols per lane -> float4 nontemporal stores; H stash is ds_write_b64.
//  - block = 2 waves, Hs wave-private 64x136 bf16 (pad 136 -> 2-way = free);
//    static LDS 34816 B -> 4 blocks/CU.
__global__ __launch_bounds__(128, 2) void k_moe(const unsigned short* __restrict__ Xb,
        const unsigned short* __restrict__ W1T, const float* __restrict__ b1,
        const unsigned short* __restrict__ W2cT, const float* __restrict__ bc2,
        float* __restrict__ out) {
    __shared__ unsigned short Hs[2][64 * 136];
    const int e    = blockIdx.y;
    const int tid  = threadIdx.x;
    const int wave = tid >> 6;               // 0..1
    const int lane = tid & 63;
    const int l15  = lane & 15;
    const int quad = lane >> 4;
    const int row0 = blockIdx.x * 128 + wave * 64;

    // ---- X B-fragments for 4 row-tiles (held in regs across both GEMM1 nt loop)
    bf16x8 xb[4][4];
    #pragma unroll
    for (int bt = 0; bt < 4; ++bt) {
        const unsigned short* xp = Xb + (size_t)(row0 + bt * 16 + l15) * 128 + quad * 8;
        #pragma unroll
        for (int kc = 0; kc < 4; ++kc)
            xb[bt][kc] = *(const bf16x8*)(xp + kc * 32);
    }

    const unsigned short* w1p = W1T + e * (128 * 128) + l15 * 128 + quad * 8;
    const float* b1p = b1 + e * 128 + quad * 4;
    unsigned short* hsw = &Hs[wave][0];

    // ---- GEMM1 (swapped): D[h'][b'] tile; lane holds h = nt*16+quad*4+r, b = bt*16+l15
    #pragma unroll
    for (int nt = 0; nt < 8; ++nt) {
        bf16x8 w[4];
        const unsigned short* bp = w1p + nt * 16 * 128;
        #pragma unroll
        for (int kc = 0; kc < 4; ++kc) w[kc] = *(const bf16x8*)(bp + kc * 32);
        float4 bias = *(const float4*)(b1p + nt * 16);      // b1[h0..h0+3], broadcast in quad
        f32x4 acc[4];
        #pragma unroll
        for (int bt = 0; bt < 4; ++bt) acc[bt] = (f32x4){bias.x, bias.y, bias.z, bias.w};
        #pragma unroll
        for (int kc = 0; kc < 4; ++kc) {
            #pragma unroll
            for (int bt = 0; bt < 4; ++bt)
                acc[bt] = __builtin_amdgcn_mfma_f32_16x16x32_bf16(w[kc], xb[bt][kc], acc[bt], 0, 0, 0);
        }
        // relu + cvt + pack 4 consecutive h per lane -> single 8B LDS write
        #pragma unroll
        for (int bt = 0; bt < 4; ++bt) {
            ushort4 hq;
            hq.x = f2bf(fmaxf(acc[bt][0], 0.f));
            hq.y = f2bf(fmaxf(acc[bt][1], 0.f));
            hq.z = f2bf(fmaxf(acc[bt][2], 0.f));
            hq.w = f2bf(fmaxf(acc[bt][3], 0.f));
            *(ushort4*)(hsw + (bt * 16 + l15) * 136 + nt * 16 + quad * 4) = hq;
        }
    }
    __syncthreads();

    // ---- H B-fragments (regs for all of GEMM2)
    bf16x8 hb[4][4];
    #pragma unroll
    for (int bt = 0; bt < 4; ++bt) {
        const unsigned short* hp = hsw + (bt * 16 + l15) * 136 + quad * 8;
        #pragma unroll
        for (int kc = 0; kc < 4; ++kc)
            hb[bt][kc] = *(const bf16x8*)(hp + kc * 32);
    }

    const unsigned short* w2p = W2cT + e * (128 * 128) + l15 * 128 + quad * 8;
    const float* bcp = bc2 + e * 128 + quad * 4;
    float* ob = out + (size_t)row0 * (NE * NC) + e * NC + quad * 4;

    // ---- GEMM2 (swapped): D[c'][b']; lane holds c = nt*16+quad*4+r (consecutive!)
    #pragma unroll
    for (int nt = 0; nt < 8; ++nt) {
        bf16x8 w[4];
        const unsigned short* bp = w2p + nt * 16 * 128;
        #pragma unroll
        for (int kc = 0; kc < 4; ++kc) w[kc] = *(const bf16x8*)(bp + kc * 32);
        float4 bias = *(const float4*)(bcp + nt * 16);
        f32x4 acc[4];
        #pragma unroll
        for (int bt = 0; bt < 4; ++bt) acc[bt] = (f32x4){bias.x, bias.y, bias.z, bias.w};
        #pragma unroll
        for (int kc = 0; kc < 4; ++kc) {
            #pragma unroll
            for (int bt = 0; bt < 4; ++bt)
                acc[bt] = __builtin_amdgcn_mfma_f32_16x16x32_bf16(w[kc], hb[bt][kc], acc[bt], 0, 0, 0);
        }
        #pragma unroll
        for (int bt = 0; bt < 4; ++bt) {
            f32x4 v = acc[bt];
            float* p = ob + (size_t)(bt * 16 + l15) * (NE * NC) + nt * 16;
            __builtin_nontemporal_store(v, (f32x4*)p);   // full 16B/lane, 64B sectors; bypass L2
        }
    }
}

extern "C" void kernel_launch(void* const* d_in, const int* in_sizes, int n_in,
                              void* d_out, int out_size, void* d_ws, size_t ws_size,
                              hipStream_t stream) {
    const float* x  = (const float*)d_in[0];
    const float* Wg = (const float*)d_in[1];
    const float* bg = (const float*)d_in[2];
    const float* W1 = (const float*)d_in[3];
    const float* b1 = (const float*)d_in[4];
    const float* W2 = (const float*)d_in[5];
    const float* b2 = (const float*)d_in[6];
    const float* Wc = (const float*)d_in[7];
    const float* bc = (const float*)d_in[8];

    float* out    = (float*)d_out;
    float* scores = out + (size_t)B_TOK * NE * NC;

    unsigned short* Xb   = (unsigned short*)d_ws;            // 32768*128 bf16 = 8 MB
    unsigned short* W1T  = Xb + (size_t)B_TOK * IN;          // 32*128*128 bf16 = 1 MB
    unsigned short* W2cT = W1T + NE * IN * HID;              // 32*128*128 bf16 = 1 MB
    float*          bc2  = (float*)(W2cT + NE * HID * NC);   // 32*128 f32 = 16 KB

    hipLaunchKernelGGL(k_convert_x, dim3((B_TOK * IN) / (256 * 4)), dim3(256), 0, stream, x, Xb);
    hipLaunchKernelGGL(k_prep_w1t,  dim3((NE * IN * HID) / 256),    dim3(256), 0, stream, W1, W1T);
    hipLaunchKernelGGL(k_prep_w2c,  dim3(NE * HID),                 dim3(128), 0, stream,
                       W2, Wc, b2, bc, W2cT, bc2);
    hipLaunchKernelGGL(k_router,    dim3(B_TOK / 8),                dim3(256), 0, stream,
                       x, Wg, bg, scores);
    // grid x = row-blocks (fastest): XCD round-robin keeps per-XCD X slice ~1MB
    // + all experts' weights 2MB resident in each 4MB L2.
    hipLaunchKernelGGL(k_moe,       dim3(B_TOK / 128, NE),          dim3(128), 0, stream,
                       Xb, W1T, b1, W2cT, bc2, out);
}

// Round 2
// 741.045 us; speedup vs baseline: 1.3876x; 1.0815x over previous
//
#include <hip/hip_runtime.h>
#include <stdint.h>

#define B_TOK 32768
#define IN    128
#define HID   128
#define NE    32
#define NC    128

typedef __attribute__((ext_vector_type(8))) __bf16 bf16x8;
typedef __attribute__((ext_vector_type(4))) float  f32x4;

static __device__ __forceinline__ unsigned short f2bf(float f) {
    union { float f; uint32_t u; } v; v.f = f;
    uint32_t u = v.u;
    return (unsigned short)((u + 0x7FFFu + ((u >> 16) & 1u)) >> 16);
}

// ---- prep: x fp32 -> bf16 --------------------------------------------------
__global__ void k_convert_x(const float* __restrict__ x, unsigned short* __restrict__ xb) {
    int i = (blockIdx.x * 256 + threadIdx.x) * 4;
    float4 v = *(const float4*)(x + i);
    ushort4 o;
    o.x = f2bf(v.x); o.y = f2bf(v.y); o.z = f2bf(v.z); o.w = f2bf(v.w);
    *(ushort4*)(xb + i) = o;
}

// ---- prep: W1T[e][h][i] = bf16(W1[e][i][h]) --------------------------------
__global__ void k_prep_w1t(const float* __restrict__ W1, unsigned short* __restrict__ W1T) {
    int idx = blockIdx.x * 256 + threadIdx.x;   // e*16384 + h*128 + i
    int i = idx & 127;
    int h = (idx >> 7) & 127;
    int e = idx >> 14;
    W1T[idx] = f2bf(W1[(e * 128 + i) * 128 + h]);
}

// ---- prep: W2cT[e][c][h] = bf16(sum_t W2[e][h][t]*Wc[t][c]); bc2 fold ------
__global__ void k_prep_w2c(const float* __restrict__ W2, const float* __restrict__ Wc,
                           const float* __restrict__ b2, const float* __restrict__ bc,
                           unsigned short* __restrict__ W2cT, float* __restrict__ bc2) {
    __shared__ float row[128];
    int e = blockIdx.x >> 7, h = blockIdx.x & 127;   // grid 32*128
    int c = threadIdx.x;                              // 128 threads
    row[c] = W2[(e * 128 + h) * 128 + c];
    __syncthreads();
    float acc = 0.f;
    #pragma unroll 8
    for (int t = 0; t < 128; ++t) acc += row[t] * Wc[t * 128 + c];   // row[t] broadcast, Wc coalesced
    W2cT[(e * 128 + c) * 128 + h] = f2bf(acc);
    if (h == 0) {
        float a2 = bc[c];
        for (int t = 0; t < 128; ++t) a2 += b2[e * 128 + t] * Wc[t * 128 + c];
        bc2[e * 128 + c] = a2;
    }
}

// ---- router: scores = softmax(relu(x @ Wg + bg), axis=1) -------------------
__global__ __launch_bounds__(256) void k_router(const float* __restrict__ x,
        const float* __restrict__ Wg, const float* __restrict__ bg,
        float* __restrict__ scores) {
    __shared__ float Wgs[128 * 32];
    __shared__ float xs[8][128];
    int tid = threadIdx.x;
    for (int j = tid; j < 4096; j += 256) Wgs[j] = Wg[j];
    int rb = blockIdx.x * 8;
    for (int j = tid; j < 8 * 128; j += 256)
        xs[j >> 7][j & 127] = x[(rb + (j >> 7)) * 128 + (j & 127)];
    __syncthreads();
    int r = tid >> 5;        // 0..7 row in tile
    int e = tid & 31;        // expert
    float acc = bg[e];
    #pragma unroll 8
    for (int i = 0; i < 128; ++i) acc += xs[r][i] * Wgs[i * 32 + e];
    acc = fmaxf(acc, 0.f);
    float m = acc;
    for (int off = 16; off > 0; off >>= 1) m = fmaxf(m, __shfl_xor(m, off, 32));
    float p = __expf(acc - m);
    float s = p;
    for (int off = 16; off > 0; off >>= 1) s += __shfl_xor(s, off, 32);
    scores[(size_t)(rb + r) * 32 + e] = p / s;
}

// ---- main fused: out[:,e,:] = relu(X@W1[e]+b1[e]) @ W2c[e] + bc2[e] --------
// v3: v2 + coalesced epilogue.
//  Round-1 counters: FETCH 12.5MB (reads L2-resident, solved) but WRITE 667MB
//  vs 536MB needed and ~2TB/s effective write BW -> store-efficiency-bound.
//  Cause: 64B scattered nontemporal chunks; each 128B line touched by two
//  different instructions -> partial-line HBM writes.
//  Fix: stage each 32-row half-tile (f32, XOR-swizzled cols) into the dead
//  Hs buffer (wave-private), read back so lanes 0..31 = one full 512B row,
//  lanes 32..63 = the next -> every store writes 8 complete 128B lines.
__global__ __launch_bounds__(128, 2) void k_moe(const unsigned short* __restrict__ Xb,
        const unsigned short* __restrict__ W1T, const float* __restrict__ b1,
        const unsigned short* __restrict__ W2cT, const float* __restrict__ bc2,
        float* __restrict__ out) {
    __shared__ __align__(16) unsigned short Hs[2][64 * 136];  // 34816 B; GEMM2 reuses as f32 stage
    const int e    = blockIdx.y;
    const int tid  = threadIdx.x;
    const int wave = tid >> 6;               // 0..1
    const int lane = tid & 63;
    const int l15  = lane & 15;
    const int quad = lane >> 4;
    const int row0 = blockIdx.x * 128 + wave * 64;

    // ---- X B-fragments for 4 row-tiles (held in regs across GEMM1)
    bf16x8 xb[4][4];
    #pragma unroll
    for (int bt = 0; bt < 4; ++bt) {
        const unsigned short* xp = Xb + (size_t)(row0 + bt * 16 + l15) * 128 + quad * 8;
        #pragma unroll
        for (int kc = 0; kc < 4; ++kc)
            xb[bt][kc] = *(const bf16x8*)(xp + kc * 32);
    }

    const unsigned short* w1p = W1T + e * (128 * 128) + l15 * 128 + quad * 8;
    const float* b1p = b1 + e * 128 + quad * 4;
    unsigned short* hsw = &Hs[wave][0];

    // ---- GEMM1 (swapped): lane holds h = nt*16+quad*4+r, b = bt*16+l15
    #pragma unroll
    for (int nt = 0; nt < 8; ++nt) {
        bf16x8 w[4];
        const unsigned short* bp = w1p + nt * 16 * 128;
        #pragma unroll
        for (int kc = 0; kc < 4; ++kc) w[kc] = *(const bf16x8*)(bp + kc * 32);
        float4 bias = *(const float4*)(b1p + nt * 16);      // b1[h0..h0+3]
        f32x4 acc[4];
        #pragma unroll
        for (int bt = 0; bt < 4; ++bt) acc[bt] = (f32x4){bias.x, bias.y, bias.z, bias.w};
        #pragma unroll
        for (int kc = 0; kc < 4; ++kc) {
            #pragma unroll
            for (int bt = 0; bt < 4; ++bt)
                acc[bt] = __builtin_amdgcn_mfma_f32_16x16x32_bf16(w[kc], xb[bt][kc], acc[bt], 0, 0, 0);
        }
        // relu + cvt + pack 4 consecutive h per lane -> single 8B LDS write
        #pragma unroll
        for (int bt = 0; bt < 4; ++bt) {
            ushort4 hq;
            hq.x = f2bf(fmaxf(acc[bt][0], 0.f));
            hq.y = f2bf(fmaxf(acc[bt][1], 0.f));
            hq.z = f2bf(fmaxf(acc[bt][2], 0.f));
            hq.w = f2bf(fmaxf(acc[bt][3], 0.f));
            *(ushort4*)(hsw + (bt * 16 + l15) * 136 + nt * 16 + quad * 4) = hq;
        }
    }
    __syncthreads();

    // ---- H B-fragments (regs for all of GEMM2)
    bf16x8 hb[4][4];
    #pragma unroll
    for (int bt = 0; bt < 4; ++bt) {
        const unsigned short* hp = hsw + (bt * 16 + l15) * 136 + quad * 8;
        #pragma unroll
        for (int kc = 0; kc < 4; ++kc)
            hb[bt][kc] = *(const bf16x8*)(hp + kc * 32);
    }
    __syncthreads();   // fence: hb reads complete before f32 stage overwrites Hs (type-pun)

    float* stage = (float*)hsw;              // wave-private [32][128] f32, col-XOR-swizzled
    const unsigned short* w2p = W2cT + e * (128 * 128) + l15 * 128 + quad * 8;
    const float* bcp = bc2 + e * 128 + quad * 4;
    const int rsel = lane >> 5;              // 0..1: which of the 2 rows this store instr covers
    const int cw   = (lane & 31) * 4;        // 32 lanes * 16B = full 512B row

    // ---- GEMM2 (swapped) in two 32-row halves; coalesced epilogue per half
    #pragma unroll
    for (int half = 0; half < 2; ++half) {
        #pragma unroll
        for (int nt = 0; nt < 8; ++nt) {
            bf16x8 w[4];
            const unsigned short* bp = w2p + nt * 16 * 128;
            #pragma unroll
            for (int kc = 0; kc < 4; ++kc) w[kc] = *(const bf16x8*)(bp + kc * 32);
            float4 bias = *(const float4*)(bcp + nt * 16);
            f32x4 acc[2];
            acc[0] = (f32x4){bias.x, bias.y, bias.z, bias.w};
            acc[1] = acc[0];
            #pragma unroll
            for (int kc = 0; kc < 4; ++kc) {
                #pragma unroll
                for (int btl = 0; btl < 2; ++btl)
                    acc[btl] = __builtin_amdgcn_mfma_f32_16x16x32_bf16(
                        w[kc], hb[half * 2 + btl][kc], acc[btl], 0, 0, 0);
            }
            #pragma unroll
            for (int btl = 0; btl < 2; ++btl) {
                int row = btl * 16 + l15;                         // 0..31 within half
                int col = (nt * 16 + quad * 4) ^ ((row & 7) << 2); // bank swizzle, 16B aligned
                *(f32x4*)(stage + row * 128 + col) = acc[btl];
            }
        }
        // readback: each instr stores 2 complete 512B rows (8 full 128B lines)
        #pragma unroll
        for (int j = 0; j < 16; ++j) {
            int row = j * 2 + rsel;
            int col = cw ^ ((row & 7) << 2);
            f32x4 v = *(const f32x4*)(stage + row * 128 + col);
            float* p = out + (size_t)(row0 + half * 32 + row) * (NE * NC) + e * NC + cw;
            __builtin_nontemporal_store(v, (f32x4*)p);
        }
    }
}

extern "C" void kernel_launch(void* const* d_in, const int* in_sizes, int n_in,
                              void* d_out, int out_size, void* d_ws, size_t ws_size,
                              hipStream_t stream) {
    const float* x  = (const float*)d_in[0];
    const float* Wg = (const float*)d_in[1];
    const float* bg = (const float*)d_in[2];
    const float* W1 = (const float*)d_in[3];
    const float* b1 = (const float*)d_in[4];
    const float* W2 = (const float*)d_in[5];
    const float* b2 = (const float*)d_in[6];
    const float* Wc = (const float*)d_in[7];
    const float* bc = (const float*)d_in[8];

    float* out    = (float*)d_out;
    float* scores = out + (size_t)B_TOK * NE * NC;

    unsigned short* Xb   = (unsigned short*)d_ws;            // 32768*128 bf16 = 8 MB
    unsigned short* W1T  = Xb + (size_t)B_TOK * IN;          // 32*128*128 bf16 = 1 MB
    unsigned short* W2cT = W1T + NE * IN * HID;              // 32*128*128 bf16 = 1 MB
    float*          bc2  = (float*)(W2cT + NE * HID * NC);   // 32*128 f32 = 16 KB

    hipLaunchKernelGGL(k_convert_x, dim3((B_TOK * IN) / (256 * 4)), dim3(256), 0, stream, x, Xb);
    hipLaunchKernelGGL(k_prep_w1t,  dim3((NE * IN * HID) / 256),    dim3(256), 0, stream, W1, W1T);
    hipLaunchKernelGGL(k_prep_w2c,  dim3(NE * HID),                 dim3(128), 0, stream,
                       W2, Wc, b2, bc, W2cT, bc2);
    hipLaunchKernelGGL(k_router,    dim3(B_TOK / 8),                dim3(256), 0, stream,
                       x, Wg, bg, scores);
    // grid x = row-blocks (fastest): XCD round-robin keeps per-XCD X slice ~1MB
    // + all experts' weights 2MB resident in each 4MB L2.
    hipLaunchKernelGGL(k_moe,       dim3(B_TOK / 128, NE),          dim3(128), 0, stream,
                       Xb, W1T, b1, W2cT, bc2, out);
}